// Round 3
// baseline (325.236 us; speedup 1.0000x reference)
//
#include <hip/hip_runtime.h>

#define SENS 200
#define DM 128
#define SEQ 96
#define BS 768            // NB*SEQ
#define NTOT 153600       // BS*SENS
#define TH 0.01f
#define BN_EPS 1e-5f
#define MPAD 224          // padded sensor dim (7*32)
#define KP 208            // effective K for phase2 / xw cols (13*16)
#define XSS 132           // xs LDS row stride in bf16 (264 B = 66 dw, gcd 2 -> free)
#define ASROW 68          // out As stride (136 B = 34 dw, gcd 2 -> free)

typedef __attribute__((ext_vector_type(8)))  __bf16 bf16x8;
typedef __attribute__((ext_vector_type(4)))  __bf16 bf16x4;
typedef __attribute__((ext_vector_type(16))) float  f32x16;

__device__ __forceinline__ f32x16 mfma32(bf16x8 a, bf16x8 b, f32x16 c) {
    return __builtin_amdgcn_mfma_f32_32x32x16_bf16(a, b, c, 0, 0, 0);
}
__device__ __forceinline__ bf16x8 join8(bf16x4 a, bf16x4 b) {
    bf16x8 r;
    #pragma unroll
    for (int j = 0; j < 4; ++j) { r[j] = a[j]; r[j + 4] = b[j]; }
    return r;
}
__device__ __forceinline__ unsigned pk2(float a, float b) {
    union { unsigned u; __bf16 hh[2]; } t;
    t.hh[0] = (__bf16)a; t.hh[1] = (__bf16)b;
    return t.u;
}
// v_permlane32_swap_b32: a' = [a.lo | b.lo], b' = [a.hi | b.hi]
__device__ __forceinline__ void permswap(unsigned &a, unsigned &b) {
    asm("v_permlane32_swap_b32 %0, %1" : "+v"(a), "+v"(b));
}
__device__ __forceinline__ bf16x8 frag4(unsigned a, unsigned b, unsigned c, unsigned d) {
    union { unsigned u[4]; bf16x8 v; } t;
    t.u[0] = a; t.u[1] = b; t.u[2] = c; t.u[3] = d;
    return t.v;
}

// ---------------- mean over 64 attention maps ----------------
__global__ void attn_mean_kernel(const float* __restrict__ attn, float* __restrict__ mapA) {
    int idx = blockIdx.x * 256 + threadIdx.x;
    if (idx >= SENS * SENS) return;
    float s = 0.f;
    #pragma unroll 8
    for (int q = 0; q < 64; ++q) s += attn[(size_t)q * SENS * SENS + idx];
    mapA[idx] = s * (1.0f / 64.0f);
}

// ---------------- symmetrize + clamp + degree ----------------
__global__ void build_map_kernel(const float* __restrict__ supports, const float* __restrict__ mapA,
                                 float* __restrict__ M, float* __restrict__ deg) {
    __shared__ float red[256];
    int m = blockIdx.x, map = blockIdx.y, j = threadIdx.x;
    const float* src = (map == 0) ? supports : mapA;
    float v = 0.f;
    if (j < SENS) {
        float sym = (m >= j) ? src[m * SENS + j] : src[j * SENS + m];
        float a = fabsf(sym);
        v = (a > TH) ? a : 0.f;
        M[(size_t)map * SENS * SENS + m * SENS + j] = v;
    }
    red[j] = v;
    __syncthreads();
    for (int off = 128; off > 0; off >>= 1) {
        if (j < off) red[j] += red[j + off];
        __syncthreads();
    }
    if (j == 0) deg[map * SENS + m] = red[0] + 1.0f;   // + self-loop
}

// ---------------- prep: An bf16 (K-sliced) | weights/bias/bnacc ----------------
__global__ __launch_bounds__(256) void prep2_kernel(
    const float* __restrict__ M, const float* __restrict__ deg,
    const float* __restrict__ W_conv, const float* __restrict__ b_conv,
    const float* __restrict__ W_out,
    __bf16* __restrict__ Anb, __bf16* __restrict__ Wt, __bf16* __restrict__ Wot,
    float* __restrict__ bsum, float* __restrict__ bnacc)
{
    const int bid = blockIdx.x, t = threadIdx.x;
    if (bid < 2 * MPAD) {
        // Anb[map][kc13][m 224][16]
        const int map = bid / MPAD, m = bid % MPAD;
        const int j = t;
        if (j < KP) {
            float val = 0.f;
            if (m < SENS && j < SENS) {
                float a = M[((size_t)map * SENS + m) * SENS + j] + ((m == j) ? 1.f : 0.f);
                val = rsqrtf(deg[map * SENS + m]) * a * rsqrtf(deg[map * SENS + j]);
            }
            Anb[(((size_t)map * 13 + (j >> 4)) * MPAD + m) * 16 + (j & 15)] = (__bf16)val;
        }
    } else {
        const int idx = (bid - 2 * MPAD) * 256 + t;
        if (idx < 32768) {                       // Wt[map][kc8][g128][16] = sum_l W[map][l][f][g]
            const int map = idx >> 14, g = (idx >> 7) & 127, f = idx & 127;
            const float* wp = W_conv + (size_t)map * 2 * DM * DM + f * DM + g;
            Wt[(((size_t)map * 8 + (f >> 4)) * DM + g) * 16 + (f & 15)] = (__bf16)(wp[0] + wp[DM * DM]);
        } else if (idx < 65536) {                // Wot[kc16][d128][16] = W_out[c][d]
            const int k = idx - 32768, d = k >> 8, c = k & 255;
            Wot[(((size_t)(c >> 4)) * DM + d) * 16 + (c & 15)] = (__bf16)W_out[c * DM + d];
        } else if (idx < 65792) {
            const int k = idx - 65536, map = k >> 7, g = k & 127;
            bsum[k] = b_conv[(map * 2) * DM + g] + b_conv[(map * 2 + 1) * DM + g];
        } else if (idx < 66304) {
            bnacc[idx - 65792] = 0.f;
        }
    }
}

// ---------------- fused conv: register-resident xw, one barrier, 8 waves ----------------
// 512 threads = 8 waves; wave = (map, g-tile): map = w>>2, gt = w&3.
//   phase1: xw C-tiles (A = x rows from LDS, B = Wt cols) -> in-register repack
//           to phase2 B-operand frags via cvt_pk + permlane32_swap (xwf[13], 26 VGPR)
//   phase2: two plain halves (mt 0..3 acc2[4], mt 4..6 acc2[3]) with inline epilogue
//           so peak live ~120 < 128. launch_bounds(512,4): VGPR<=128, 2 blk/CU = 16 waves/CU.
__global__ __launch_bounds__(512, 4) void conv_kernel(
    const float* __restrict__ x, const __bf16* __restrict__ Anb,
    const __bf16* __restrict__ Wt, const float* __restrict__ bsum,
    __bf16* __restrict__ h, float* __restrict__ bnacc)
{
    __shared__ __bf16 xs[MPAD * XSS];             // 59136 B -> 2 blocks/CU
    const int bs = blockIdx.x;
    const int b = bs / SEQ, s = bs % SEQ;
    const int t = threadIdx.x;
    const int w = t >> 6, lane = t & 63;
    const int map = w >> 2, gt = w & 3;
    const int l31 = lane & 31, hi = lane >> 5;

    // ---- stage x[b, :, s, :] -> bf16 LDS; rows 200..223 zeroed ----
    {
        const float* xb = x + ((size_t)b * SENS * SEQ + s) * DM;
        for (int i = t; i < SENS * 32; i += 512) {
            const int n = i >> 5, c = i & 31;
            const float4 v = *(const float4*)(xb + (size_t)n * SEQ * DM + c * 4);
            union { uint2 u; __bf16 hh[4]; } p;
            p.hh[0] = (__bf16)v.x; p.hh[1] = (__bf16)v.y;
            p.hh[2] = (__bf16)v.z; p.hh[3] = (__bf16)v.w;
            *(uint2*)(&xs[n * XSS + c * 4]) = p.u;
        }
        unsigned* zp = (unsigned*)(&xs[SENS * XSS]);
        for (int i = t; i < (MPAD - SENS) * (XSS / 2); i += 512) zp[i] = 0u;
    }
    __syncthreads();                              // the only barrier

    // ---- phase 1: xw frags for this wave's (map, g-tile), all n ----
    bf16x8 xwf[13];
    {
        bf16x8 wf[8];
        const __bf16* wb = Wt + (((size_t)map * 8) * DM + gt * 32 + l31) * 16 + hi * 8;
        #pragma unroll
        for (int k = 0; k < 8; ++k) wf[k] = *(const bf16x8*)(wb + (size_t)k * DM * 16);
        #pragma unroll
        for (int nt = 0; nt < 7; ++nt) {
            f32x16 acc;
            #pragma unroll
            for (int r = 0; r < 16; ++r) acc[r] = 0.f;
            const __bf16* xp = &xs[(nt * 32 + l31) * XSS + hi * 8];
            #pragma unroll
            for (int k = 0; k < 8; ++k)
                acc = mfma32(*(const bf16x8*)(xp + k * 16), wf[k], acc);
            // repack C[row=n][col=g] -> B-op frag (k=n): half-exchange across hi
            {
                unsigned w0 = pk2(acc[0], acc[1]),  w1 = pk2(acc[2], acc[3]);
                unsigned w2 = pk2(acc[4], acc[5]),  w3 = pk2(acc[6], acc[7]);
                permswap(w0, w2); permswap(w1, w3);
                xwf[2 * nt] = frag4(w0, w1, w2, w3);
            }
            if (nt < 6) {
                unsigned w0 = pk2(acc[8], acc[9]),   w1 = pk2(acc[10], acc[11]);
                unsigned w2 = pk2(acc[12], acc[13]), w3 = pk2(acc[14], acc[15]);
                permswap(w0, w2); permswap(w1, w3);
                xwf[2 * nt + 1] = frag4(w0, w1, w2, w3);
            }
        }
    }

    // ---- phase 2 + epilogue, two halves ----
    const float bias = bsum[map * DM + gt * 32 + l31];
    float sv = 0.f, qv = 0.f;
    const __bf16* abase = Anb + (((size_t)map * 13) * MPAD + l31) * 16 + hi * 8;

    // half A: mt = 0..3
    {
        f32x16 acc2[4];
        #pragma unroll
        for (int mi = 0; mi < 4; ++mi)
            #pragma unroll
            for (int r = 0; r < 16; ++r) acc2[mi][r] = 0.f;
        #pragma unroll
        for (int kc = 0; kc < 13; ++kc) {
            const __bf16* ap = abase + (size_t)kc * MPAD * 16;
            #pragma unroll
            for (int mi = 0; mi < 4; ++mi)
                acc2[mi] = mfma32(*(const bf16x8*)(ap + mi * 32 * 16), xwf[kc], acc2[mi]);
        }
        #pragma unroll
        for (int mi = 0; mi < 4; ++mi) {
            const int mt = mi;
            bf16x8 h0, h1;
            #pragma unroll
            for (int r = 0; r < 16; ++r) {
                const float v = acc2[mi][r] + bias;
                if (r < 8) h0[r] = (__bf16)v; else h1[r - 8] = (__bf16)v;
                const int m = mt * 32 + (r & 3) + 8 * (r >> 2) + 4 * hi;
                if (m < SENS) { sv += v; qv += v * v; }
            }
            __bf16* hp = h + ((((size_t)(bs * 2 + map) * 7 + mt) * 4 + gt) * 64 + lane) * 16;
            *(bf16x8*)hp = h0;
            *(bf16x8*)(hp + 8) = h1;
        }
    }

    // half B: mt = 4..6
    {
        f32x16 acc2[3];
        #pragma unroll
        for (int mi = 0; mi < 3; ++mi)
            #pragma unroll
            for (int r = 0; r < 16; ++r) acc2[mi][r] = 0.f;
        #pragma unroll
        for (int kc = 0; kc < 13; ++kc) {
            const __bf16* ap = abase + ((size_t)kc * MPAD + 4 * 32) * 16;
            #pragma unroll
            for (int mi = 0; mi < 3; ++mi)
                acc2[mi] = mfma32(*(const bf16x8*)(ap + mi * 32 * 16), xwf[kc], acc2[mi]);
        }
        #pragma unroll
        for (int mi = 0; mi < 3; ++mi) {
            const int mt = 4 + mi;
            bf16x8 h0, h1;
            #pragma unroll
            for (int r = 0; r < 16; ++r) {
                const float v = acc2[mi][r] + bias;
                if (r < 8) h0[r] = (__bf16)v; else h1[r - 8] = (__bf16)v;
                const int m = mt * 32 + (r & 3) + 8 * (r >> 2) + 4 * hi;
                if (m < SENS) { sv += v; qv += v * v; }
            }
            __bf16* hp = h + ((((size_t)(bs * 2 + map) * 7 + mt) * 4 + gt) * 64 + lane) * 16;
            *(bf16x8*)hp = h0;
            *(bf16x8*)(hp + 8) = h1;
        }
    }

    sv += __shfl_xor(sv, 32);
    qv += __shfl_xor(qv, 32);
    if (hi == 0) {
        atomicAdd(&bnacc[map * DM + gt * 32 + l31], sv);
        atomicAdd(&bnacc[256 + map * DM + gt * 32 + l31], qv);
    }
}

// stage chunk cn of relu(bn(h)) into As buffer (224 rows x 64 cols)
__device__ __forceinline__ void out_stage(int cn, int t, int bs,
                                          const __bf16* __restrict__ h,
                                          const float* sc_s, const float* sh_s,
                                          __bf16* dst)
{
    const int mapn = cn >> 1;
    const __bf16* hb = h + ((size_t)(bs * 2 + mapn) * 28 + (cn & 1) * 2) * 1024;
    bf16x8 vv[4];
    #pragma unroll
    for (int it = 0; it < 4; ++it) {
        const int idx = it * 512 + t;
        if (idx < 1792)
            vv[it] = *(const bf16x8*)(hb + ((size_t)(idx >> 8) * 4 + ((idx >> 7) & 1)) * 1024
                                          + ((idx >> 1) & 63) * 16 + (idx & 1) * 8);
    }
    #pragma unroll
    for (int it = 0; it < 4; ++it) {
        const int idx = it * 512 + t;
        if (idx < 1792) {
            const int half = idx & 1, lane_s = (idx >> 1) & 63;
            const int ctl = (idx >> 7) & 1, strip = idx >> 8;
            const int cl = ctl * 32 + (lane_s & 31);
            const int cg = mapn * DM + (cn & 1) * 64 + cl;
            const float scv = sc_s[cg], shv = sh_s[cg];
            const int mbase = strip * 32 + 4 * (lane_s >> 5) + 16 * half;
            #pragma unroll
            for (int q2 = 0; q2 < 8; ++q2) {
                const int row = mbase + (q2 & 3) + 8 * (q2 >> 2);
                const float fv = (float)vv[it][q2] * scv + shv;
                dst[row * ASROW + cl] = (__bf16)fmaxf(fv, 0.f);
            }
        }
    }
}

// ---------------- out: relu( relu(bn(h)) cat @ W_out + b_out ), double-buffered ----------------
__global__ __launch_bounds__(512) void out_kernel(
    const __bf16* __restrict__ h, const __bf16* __restrict__ Wot,
    const float* __restrict__ bnacc,
    const float* __restrict__ gamma, const float* __restrict__ beta,
    const float* __restrict__ b_out, float* __restrict__ out)
{
    __shared__ __bf16 As[2][MPAD * ASROW];        // 2 x 30464 B
    __shared__ float sc_s[256], sh_s[256];
    const int bs = blockIdx.x;
    const int b = bs / SEQ, s = bs % SEQ;
    const int t = threadIdx.x, w = t >> 6, lane = t & 63;
    const int l31 = lane & 31, hi = lane >> 5;
    const int dct = w & 3, sbase = w >> 2;
    if (t < 256) {                                // BN finalize (fused, per-block)
        const float mu = bnacc[t] * (1.f / (float)NTOT);
        const float var = bnacc[256 + t] * (1.f / (float)NTOT) - mu * mu;
        const float sc = gamma[t] * rsqrtf(var + BN_EPS);
        sc_s[t] = sc;
        sh_s[t] = beta[t] - mu * sc;
    }
    f32x16 acc[4];
    {
        const float bo = b_out[dct * 32 + l31];
        #pragma unroll
        for (int i = 0; i < 4; ++i)
            #pragma unroll
            for (int r = 0; r < 16; ++r) acc[i][r] = bo;
    }
    __syncthreads();
    out_stage(0, t, bs, h, sc_s, sh_s, &As[0][0]);
    __syncthreads();
    for (int c = 0; c < 4; ++c) {
        #pragma unroll
        for (int kc = 0; kc < 4; ++kc) {
            bf16x8 bfrag = *(const bf16x8*)(Wot + ((size_t)(c * 4 + kc) * DM + dct * 32 + l31) * 16 + hi * 8);
            #pragma unroll
            for (int i = 0; i < 4; ++i) {
                const int strip = sbase + 2 * i;
                if (strip >= 7) break;
                const __bf16* ap = &As[c & 1][(strip * 32 + l31) * ASROW + kc * 16 + hi * 8];
                acc[i] = mfma32(join8(*(const bf16x4*)ap, *(const bf16x4*)(ap + 4)), bfrag, acc[i]);
            }
        }
        if (c < 3) out_stage(c + 1, t, bs, h, sc_s, sh_s, &As[(c + 1) & 1][0]);
        __syncthreads();
    }
    #pragma unroll
    for (int i = 0; i < 4; ++i) {
        const int strip = sbase + 2 * i;
        if (strip >= 7) break;
        #pragma unroll
        for (int r = 0; r < 16; ++r) {
            const int m = strip * 32 + (r & 3) + 8 * (r >> 2) + 4 * hi;
            if (m < SENS)
                out[(((size_t)b * SENS + m) * SEQ + s) * DM + dct * 32 + l31] = fmaxf(acc[i][r], 0.f);
        }
    }
}

extern "C" void kernel_launch(void* const* d_in, const int* in_sizes, int n_in,
                              void* d_out, int out_size, void* d_ws, size_t ws_size,
                              hipStream_t stream) {
    const float* x        = (const float*)d_in[0];
    const float* attn     = (const float*)d_in[1];
    const float* supports = (const float*)d_in[2];
    const float* W_conv   = (const float*)d_in[3];
    const float* b_conv   = (const float*)d_in[4];
    const float* gamma    = (const float*)d_in[5];
    const float* beta     = (const float*)d_in[6];
    const float* W_out    = (const float*)d_in[7];
    const float* b_out    = (const float*)d_in[8];
    float* out = (float*)d_out;
    char* base = (char*)d_ws;

    float*  mapA  = (float*)(base + 0);          // 160000
    float*  Mbuf  = (float*)(base + 160000);     // 320000
    float*  deg   = (float*)(base + 480000);     // 1600
    float*  bnacc = (float*)(base + 481664);     // 2048
    float*  bsum  = (float*)(base + 483712);     // 1024
    __bf16* Wt    = (__bf16*)(base + 484736);    // 65536
    __bf16* Wot   = (__bf16*)(base + 550272);    // 65536
    __bf16* Anb   = (__bf16*)(base + 615808);    // 186368
    __bf16* h     = (__bf16*)(base + 1048576);   // 88080384 (end ~85 MiB)

    attn_mean_kernel<<<157, 256, 0, stream>>>(attn, mapA);
    build_map_kernel<<<dim3(SENS, 2), 256, 0, stream>>>(supports, mapA, Mbuf, deg);
    prep2_kernel<<<2 * MPAD + 260, 256, 0, stream>>>(Mbuf, deg, W_conv, b_conv, W_out,
                                                     Anb, Wt, Wot, bsum, bnacc);
    conv_kernel<<<BS, 512, 0, stream>>>(x, Anb, Wt, bsum, h, bnacc);
    out_kernel<<<BS, 512, 0, stream>>>(h, Wot, bnacc, gamma, beta, b_out, out);
}

// Round 4
// 273.206 us; speedup vs baseline: 1.1904x; 1.1904x over previous
//
#include <hip/hip_runtime.h>

#define SENS 200
#define DM 128
#define SEQ 96
#define NB 8
#define BS 768            // NB*SEQ
#define NTOT 153600       // BS*SENS
#define TH 0.01f
#define BN_EPS 1e-5f
#define MPAD 224          // padded sensor dim (7*32)
#define KP 208            // effective K for phase2 / xw cols (13*16)
#define XWS 212           // xw LDS row stride (424 B = 106 dw, gcd 2 -> free)
#define ASROW 68          // out As stride (136 B = 34 dw, gcd 2 -> free)

typedef __attribute__((ext_vector_type(8)))  __bf16 bf16x8;
typedef __attribute__((ext_vector_type(4)))  __bf16 bf16x4;
typedef __attribute__((ext_vector_type(16))) float  f32x16;

__device__ __forceinline__ f32x16 mfma32(bf16x8 a, bf16x8 b, f32x16 c) {
    return __builtin_amdgcn_mfma_f32_32x32x16_bf16(a, b, c, 0, 0, 0);
}
__device__ __forceinline__ bf16x8 join8(bf16x4 a, bf16x4 b) {
    bf16x8 r;
    #pragma unroll
    for (int j = 0; j < 4; ++j) { r[j] = a[j]; r[j + 4] = b[j]; }
    return r;
}

// ---------------- mean over 64 attention maps ----------------
__global__ void attn_mean_kernel(const float* __restrict__ attn, float* __restrict__ mapA) {
    int idx = blockIdx.x * 256 + threadIdx.x;
    if (idx >= SENS * SENS) return;
    float s = 0.f;
    #pragma unroll 8
    for (int q = 0; q < 64; ++q) s += attn[(size_t)q * SENS * SENS + idx];
    mapA[idx] = s * (1.0f / 64.0f);
}

// ---------------- symmetrize + clamp + degree ----------------
__global__ void build_map_kernel(const float* __restrict__ supports, const float* __restrict__ mapA,
                                 float* __restrict__ M, float* __restrict__ deg) {
    __shared__ float red[256];
    int m = blockIdx.x, map = blockIdx.y, j = threadIdx.x;
    const float* src = (map == 0) ? supports : mapA;
    float v = 0.f;
    if (j < SENS) {
        float sym = (m >= j) ? src[m * SENS + j] : src[j * SENS + m];
        float a = fabsf(sym);
        v = (a > TH) ? a : 0.f;
        M[(size_t)map * SENS * SENS + m * SENS + j] = v;
    }
    red[j] = v;
    __syncthreads();
    for (int off = 128; off > 0; off >>= 1) {
        if (j < off) red[j] += red[j + off];
        __syncthreads();
    }
    if (j == 0) deg[map * SENS + m] = red[0] + 1.0f;   // + self-loop
}

// ---------------- prep: An bf16 (K-sliced) | weights/bias/bnacc ----------------
__global__ __launch_bounds__(256) void prep2_kernel(
    const float* __restrict__ M, const float* __restrict__ deg,
    const float* __restrict__ W_conv, const float* __restrict__ b_conv,
    const float* __restrict__ W_out,
    __bf16* __restrict__ Anb, __bf16* __restrict__ Wt, __bf16* __restrict__ Wot,
    float* __restrict__ bsum, float* __restrict__ bnacc)
{
    const int bid = blockIdx.x, t = threadIdx.x;
    if (bid < 2 * MPAD) {
        // Anb[map][kc13][m 224][16]
        const int map = bid / MPAD, m = bid % MPAD;
        const int j = t;
        if (j < KP) {
            float val = 0.f;
            if (m < SENS && j < SENS) {
                float a = M[((size_t)map * SENS + m) * SENS + j] + ((m == j) ? 1.f : 0.f);
                val = rsqrtf(deg[map * SENS + m]) * a * rsqrtf(deg[map * SENS + j]);
            }
            Anb[(((size_t)map * 13 + (j >> 4)) * MPAD + m) * 16 + (j & 15)] = (__bf16)val;
        }
    } else {
        const int idx = (bid - 2 * MPAD) * 256 + t;
        if (idx < 32768) {                       // Wt[map][kc8][g128][16] = sum_l W[map][l][f][g]
            const int map = idx >> 14, g = (idx >> 7) & 127, f = idx & 127;
            const float* wp = W_conv + (size_t)map * 2 * DM * DM + f * DM + g;
            Wt[(((size_t)map * 8 + (f >> 4)) * DM + g) * 16 + (f & 15)] = (__bf16)(wp[0] + wp[DM * DM]);
        } else if (idx < 65536) {                // Wot[kc16][d128][16] = W_out[c][d]
            const int k = idx - 32768, d = k >> 8, c = k & 255;
            Wot[(((size_t)(c >> 4)) * DM + d) * 16 + (c & 15)] = (__bf16)W_out[c * DM + d];
        } else if (idx < 65792) {
            const int k = idx - 65536, map = k >> 7, g = k & 127;
            bsum[k] = b_conv[(map * 2) * DM + g] + b_conv[(map * 2 + 1) * DM + g];
        } else if (idx < 66304) {
            bnacc[idx - 65792] = 0.f;
        }
    }
}

// ---------------- fused conv: g-split staging for occupancy ----------------
// 448 threads = 7 waves. 4 passes (map, g-half): phase1 stages xw[64 gl][208 n]
// (wave = n-tile, 2 g-tiles), phase2 computes h-strip (wave = m-strip, 2 g-tiles).
// LDS 27.1 KB xw + 3.6 KB bnred = 30.7 KB -> 4 blocks/CU (wave-capped, 28 waves = 87%).
// launch_bounds(448,7) pins VGPR<=72 (live set ~60: acc[2]/acc2[2] = 32 + frags).
// BN partials: per-pass wave-reduced into bnred LDS, flushed by t<128 next pass.
__global__ __launch_bounds__(448, 7) void conv_kernel(
    const float* __restrict__ x, const __bf16* __restrict__ Anb,
    const __bf16* __restrict__ Wt, const float* __restrict__ bsum,
    __bf16* __restrict__ h, float* __restrict__ bnacc)
{
    __shared__ __bf16 xw[64 * XWS];               // 27136 B
    __shared__ float bnred[2 * 7 * 64];           // 3584 B
    const int bs = blockIdx.x;
    const int b = bs / SEQ, s = bs % SEQ;
    const int t = threadIdx.x, w = t >> 6, lane = t & 63;
    const int l31 = lane & 31, hi = lane >> 5;

    const int n = w * 32 + l31;
    const bool valid = (n < SENS);
    const float* xrow = x + (((size_t)b * SENS + (valid ? n : 0)) * SEQ + s) * DM + hi * 8;

    #pragma unroll 1
    for (int mh = 0; mh < 4; ++mh) {              // map = mh>>1, g-half = mh&1
        const int map = mh >> 1, gh = mh & 1;
        if (mh) __syncthreads();                  // prev phase2 reads + bnred writes done
        if (mh && t < 128) {                      // flush BN partials of prev pass
            const int pm = (mh - 1) >> 1, pg = (mh - 1) & 1;
            const int sq = t >> 6, gl = t & 63;
            float ssum = 0.f;
            #pragma unroll
            for (int k = 0; k < 7; ++k) ssum += bnred[(sq * 7 + k) * 64 + gl];
            atomicAdd(&bnacc[sq * 256 + pm * DM + pg * 64 + gl], ssum);
        }
        // ---- phase 1: xw[gl 64][n 208] = Wt[map][:, gh*64+gl] @ xr^T (n-tile = w) ----
        {
            f32x16 acc[2];
            #pragma unroll
            for (int gt2 = 0; gt2 < 2; ++gt2)
                #pragma unroll
                for (int r = 0; r < 16; ++r) acc[gt2][r] = 0.f;
            const __bf16* wb = Wt + (((size_t)map * 8) * DM + gh * 64 + l31) * 16 + hi * 8;
            #pragma unroll
            for (int kc = 0; kc < 8; ++kc) {
                float4 v0 = *(const float4*)(xrow + kc * 16);
                float4 v1 = *(const float4*)(xrow + kc * 16 + 4);
                bf16x8 bfrag;
                bfrag[0] = (__bf16)v0.x; bfrag[1] = (__bf16)v0.y;
                bfrag[2] = (__bf16)v0.z; bfrag[3] = (__bf16)v0.w;
                bfrag[4] = (__bf16)v1.x; bfrag[5] = (__bf16)v1.y;
                bfrag[6] = (__bf16)v1.z; bfrag[7] = (__bf16)v1.w;
                if (!valid) {
                    #pragma unroll
                    for (int j = 0; j < 8; ++j) bfrag[j] = (__bf16)0.f;
                }
                const __bf16* wp = wb + (size_t)kc * DM * 16;
                acc[0] = mfma32(*(const bf16x8*)wp, bfrag, acc[0]);
                acc[1] = mfma32(*(const bf16x8*)(wp + 32 * 16), bfrag, acc[1]);
            }
            if (n < KP) {
                #pragma unroll
                for (int gt2 = 0; gt2 < 2; ++gt2)
                    #pragma unroll
                    for (int r = 0; r < 16; ++r) {
                        const int gl = gt2 * 32 + (r & 3) + 8 * (r >> 2) + 4 * hi;
                        xw[gl * XWS + n] = (__bf16)acc[gt2][r];
                    }
            }
        }
        __syncthreads();

        // ---- phase 2: h-strip w = An[strip] @ xw^T (K=208) ----
        f32x16 acc2[2];
        #pragma unroll
        for (int gt2 = 0; gt2 < 2; ++gt2)
            #pragma unroll
            for (int r = 0; r < 16; ++r) acc2[gt2][r] = 0.f;
        {
            const __bf16* ab = Anb + (((size_t)map * 13) * MPAD + w * 32 + l31) * 16 + hi * 8;
            #pragma unroll 2
            for (int kc = 0; kc < 13; ++kc) {
                bf16x8 afrag = *(const bf16x8*)(ab + (size_t)kc * MPAD * 16);
                #pragma unroll
                for (int gt2 = 0; gt2 < 2; ++gt2) {
                    bf16x8 bfrag = *(const bf16x8*)(xw + (gt2 * 32 + l31) * XWS + kc * 16 + hi * 8);
                    acc2[gt2] = mfma32(afrag, bfrag, acc2[gt2]);
                }
            }
        }
        // ---- epilogue: bias, h store (layout unchanged), BN partials -> bnred ----
        #pragma unroll
        for (int gt2 = 0; gt2 < 2; ++gt2) {
            const int gt = gh * 2 + gt2;
            const float bias = bsum[map * DM + gt * 32 + l31];
            bf16x8 h0, h1;
            float s2 = 0.f, q = 0.f;
            #pragma unroll
            for (int r = 0; r < 16; ++r) {
                const float v = acc2[gt2][r] + bias;
                if (r < 8) h0[r] = (__bf16)v; else h1[r - 8] = (__bf16)v;
                const int m = w * 32 + (r & 3) + 8 * (r >> 2) + 4 * hi;
                if (m < SENS) { s2 += v; q += v * v; }
            }
            __bf16* hp = h + ((((size_t)(bs * 2 + map) * 7 + w) * 4 + gt) * 64 + lane) * 16;
            *(bf16x8*)hp = h0;
            *(bf16x8*)(hp + 8) = h1;
            s2 += __shfl_xor(s2, 32);
            q  += __shfl_xor(q, 32);
            if (hi == 0) {
                bnred[(0 * 7 + w) * 64 + gt2 * 32 + l31] = s2;
                bnred[(1 * 7 + w) * 64 + gt2 * 32 + l31] = q;
            }
        }
    }
    __syncthreads();
    if (t < 128) {                                // flush BN partials of last pass (map1, gh1)
        const int sq = t >> 6, gl = t & 63;
        float ssum = 0.f;
        #pragma unroll
        for (int k = 0; k < 7; ++k) ssum += bnred[(sq * 7 + k) * 64 + gl];
        atomicAdd(&bnacc[sq * 256 + DM + 64 + gl], ssum);
    }
}

// stage chunk cn of relu(bn(h)) into As buffer (224 rows x 64 cols)
__device__ __forceinline__ void out_stage(int cn, int t, int bs,
                                          const __bf16* __restrict__ h,
                                          const float* sc_s, const float* sh_s,
                                          __bf16* dst)
{
    const int mapn = cn >> 1;
    const __bf16* hb = h + ((size_t)(bs * 2 + mapn) * 28 + (cn & 1) * 2) * 1024;
    bf16x8 vv[4];
    #pragma unroll
    for (int it = 0; it < 4; ++it) {
        const int idx = it * 512 + t;
        if (idx < 1792)
            vv[it] = *(const bf16x8*)(hb + ((size_t)(idx >> 8) * 4 + ((idx >> 7) & 1)) * 1024
                                          + ((idx >> 1) & 63) * 16 + (idx & 1) * 8);
    }
    #pragma unroll
    for (int it = 0; it < 4; ++it) {
        const int idx = it * 512 + t;
        if (idx < 1792) {
            const int half = idx & 1, lane_s = (idx >> 1) & 63;
            const int ctl = (idx >> 7) & 1, strip = idx >> 8;
            const int cl = ctl * 32 + (lane_s & 31);
            const int cg = mapn * DM + (cn & 1) * 64 + cl;
            const float scv = sc_s[cg], shv = sh_s[cg];
            const int mbase = strip * 32 + 4 * (lane_s >> 5) + 16 * half;
            #pragma unroll
            for (int q2 = 0; q2 < 8; ++q2) {
                const int row = mbase + (q2 & 3) + 8 * (q2 >> 2);
                const float fv = (float)vv[it][q2] * scv + shv;
                dst[row * ASROW + cl] = (__bf16)fmaxf(fv, 0.f);
            }
        }
    }
}

// ---------------- out: relu( relu(bn(h)) cat @ W_out + b_out ), double-buffered ----------------
__global__ __launch_bounds__(512) void out_kernel(
    const __bf16* __restrict__ h, const __bf16* __restrict__ Wot,
    const float* __restrict__ bnacc,
    const float* __restrict__ gamma, const float* __restrict__ beta,
    const float* __restrict__ b_out, float* __restrict__ out)
{
    __shared__ __bf16 As[2][MPAD * ASROW];        // 2 x 30464 B
    __shared__ float sc_s[256], sh_s[256];
    const int bs = blockIdx.x;
    const int b = bs / SEQ, s = bs % SEQ;
    const int t = threadIdx.x, w = t >> 6, lane = t & 63;
    const int l31 = lane & 31, hi = lane >> 5;
    const int dct = w & 3, sbase = w >> 2;
    if (t < 256) {                                // BN finalize (fused, per-block)
        const float mu = bnacc[t] * (1.f / (float)NTOT);
        const float var = bnacc[256 + t] * (1.f / (float)NTOT) - mu * mu;
        const float sc = gamma[t] * rsqrtf(var + BN_EPS);
        sc_s[t] = sc;
        sh_s[t] = beta[t] - mu * sc;
    }
    f32x16 acc[4];
    {
        const float bo = b_out[dct * 32 + l31];
        #pragma unroll
        for (int i = 0; i < 4; ++i)
            #pragma unroll
            for (int r = 0; r < 16; ++r) acc[i][r] = bo;
    }
    __syncthreads();
    out_stage(0, t, bs, h, sc_s, sh_s, &As[0][0]);
    __syncthreads();
    for (int c = 0; c < 4; ++c) {
        #pragma unroll
        for (int kc = 0; kc < 4; ++kc) {
            bf16x8 bfrag = *(const bf16x8*)(Wot + ((size_t)(c * 4 + kc) * DM + dct * 32 + l31) * 16 + hi * 8);
            #pragma unroll
            for (int i = 0; i < 4; ++i) {
                const int strip = sbase + 2 * i;
                if (strip >= 7) break;
                const __bf16* ap = &As[c & 1][(strip * 32 + l31) * ASROW + kc * 16 + hi * 8];
                acc[i] = mfma32(join8(*(const bf16x4*)ap, *(const bf16x4*)(ap + 4)), bfrag, acc[i]);
            }
        }
        if (c < 3) out_stage(c + 1, t, bs, h, sc_s, sh_s, &As[(c + 1) & 1][0]);
        __syncthreads();
    }
    #pragma unroll
    for (int i = 0; i < 4; ++i) {
        const int strip = sbase + 2 * i;
        if (strip >= 7) break;
        #pragma unroll
        for (int r = 0; r < 16; ++r) {
            const int m = strip * 32 + (r & 3) + 8 * (r >> 2) + 4 * hi;
            if (m < SENS)
                out[(((size_t)b * SENS + m) * SEQ + s) * DM + dct * 32 + l31] = fmaxf(acc[i][r], 0.f);
        }
    }
}

extern "C" void kernel_launch(void* const* d_in, const int* in_sizes, int n_in,
                              void* d_out, int out_size, void* d_ws, size_t ws_size,
                              hipStream_t stream) {
    const float* x        = (const float*)d_in[0];
    const float* attn     = (const float*)d_in[1];
    const float* supports = (const float*)d_in[2];
    const float* W_conv   = (const float*)d_in[3];
    const float* b_conv   = (const float*)d_in[4];
    const float* gamma    = (const float*)d_in[5];
    const float* beta     = (const float*)d_in[6];
    const float* W_out    = (const float*)d_in[7];
    const float* b_out    = (const float*)d_in[8];
    float* out = (float*)d_out;
    char* base = (char*)d_ws;

    float*  mapA  = (float*)(base + 0);          // 160000
    float*  Mbuf  = (float*)(base + 160000);     // 320000
    float*  deg   = (float*)(base + 480000);     // 1600
    float*  bnacc = (float*)(base + 481664);     // 2048
    float*  bsum  = (float*)(base + 483712);     // 1024
    __bf16* Wt    = (__bf16*)(base + 484736);    // 65536
    __bf16* Wot   = (__bf16*)(base + 550272);    // 65536
    __bf16* Anb   = (__bf16*)(base + 615808);    // 186368
    __bf16* h     = (__bf16*)(base + 1048576);   // 88080384 (end ~85 MiB)

    attn_mean_kernel<<<157, 256, 0, stream>>>(attn, mapA);
    build_map_kernel<<<dim3(SENS, 2), 256, 0, stream>>>(supports, mapA, Mbuf, deg);
    prep2_kernel<<<2 * MPAD + 260, 256, 0, stream>>>(Mbuf, deg, W_conv, b_conv, W_out,
                                                     Anb, Wt, Wot, bsum, bnacc);
    conv_kernel<<<BS, 448, 0, stream>>>(x, Anb, Wt, bsum, h, bnacc);
    out_kernel<<<BS, 512, 0, stream>>>(h, Wot, bnacc, gamma, beta, b_out, out);
}

// Round 5
// 262.006 us; speedup vs baseline: 1.2413x; 1.0427x over previous
//
#include <hip/hip_runtime.h>

#define SENS 200
#define DM 128
#define SEQ 96
#define NB 8
#define BS 768            // NB*SEQ
#define NTOT 153600       // BS*SENS
#define TH 0.01f
#define BN_EPS 1e-5f
#define MPAD 224          // padded sensor dim (7*32)
#define KP 208            // effective K for phase2 / xw cols (13*16)
#define XWS 210           // xw LDS row stride (420 B = 105 dw, gcd 1 -> conflict-free)
                          // 128*210*2 = 53760 B -> 3 blocks/CU (zero tail: 768 = 3*256)
#define ASROW 68          // out As stride (136 B = 34 dw, gcd 2 -> free)

typedef __attribute__((ext_vector_type(8)))  __bf16 bf16x8;
typedef __attribute__((ext_vector_type(4)))  __bf16 bf16x4;
typedef __attribute__((ext_vector_type(16))) float  f32x16;

__device__ __forceinline__ f32x16 mfma32(bf16x8 a, bf16x8 b, f32x16 c) {
    return __builtin_amdgcn_mfma_f32_32x32x16_bf16(a, b, c, 0, 0, 0);
}
__device__ __forceinline__ bf16x8 join8(bf16x4 a, bf16x4 b) {
    bf16x8 r;
    #pragma unroll
    for (int j = 0; j < 4; ++j) { r[j] = a[j]; r[j + 4] = b[j]; }
    return r;
}

// ---------------- mean over 64 attention maps ----------------
__global__ void attn_mean_kernel(const float* __restrict__ attn, float* __restrict__ mapA) {
    int idx = blockIdx.x * 256 + threadIdx.x;
    if (idx >= SENS * SENS) return;
    float s = 0.f;
    #pragma unroll 8
    for (int q = 0; q < 64; ++q) s += attn[(size_t)q * SENS * SENS + idx];
    mapA[idx] = s * (1.0f / 64.0f);
}

// ---------------- symmetrize + clamp + degree ----------------
__global__ void build_map_kernel(const float* __restrict__ supports, const float* __restrict__ mapA,
                                 float* __restrict__ M, float* __restrict__ deg) {
    __shared__ float red[256];
    int m = blockIdx.x, map = blockIdx.y, j = threadIdx.x;
    const float* src = (map == 0) ? supports : mapA;
    float v = 0.f;
    if (j < SENS) {
        float sym = (m >= j) ? src[m * SENS + j] : src[j * SENS + m];
        float a = fabsf(sym);
        v = (a > TH) ? a : 0.f;
        M[(size_t)map * SENS * SENS + m * SENS + j] = v;
    }
    red[j] = v;
    __syncthreads();
    for (int off = 128; off > 0; off >>= 1) {
        if (j < off) red[j] += red[j + off];
        __syncthreads();
    }
    if (j == 0) deg[map * SENS + m] = red[0] + 1.0f;   // + self-loop
}

// ---------------- prep: An bf16 (K-sliced) | weights/bias/bnacc ----------------
__global__ __launch_bounds__(256) void prep2_kernel(
    const float* __restrict__ M, const float* __restrict__ deg,
    const float* __restrict__ W_conv, const float* __restrict__ b_conv,
    const float* __restrict__ W_out,
    __bf16* __restrict__ Anb, __bf16* __restrict__ Wt, __bf16* __restrict__ Wot,
    float* __restrict__ bsum, float* __restrict__ bnacc)
{
    const int bid = blockIdx.x, t = threadIdx.x;
    if (bid < 2 * MPAD) {
        // Anb[map][kc13][m 224][16]
        const int map = bid / MPAD, m = bid % MPAD;
        const int j = t;
        if (j < KP) {
            float val = 0.f;
            if (m < SENS && j < SENS) {
                float a = M[((size_t)map * SENS + m) * SENS + j] + ((m == j) ? 1.f : 0.f);
                val = rsqrtf(deg[map * SENS + m]) * a * rsqrtf(deg[map * SENS + j]);
            }
            Anb[(((size_t)map * 13 + (j >> 4)) * MPAD + m) * 16 + (j & 15)] = (__bf16)val;
        }
    } else {
        const int idx = (bid - 2 * MPAD) * 256 + t;
        if (idx < 32768) {                       // Wt[map][kc8][g128][16] = sum_l W[map][l][f][g]
            const int map = idx >> 14, g = (idx >> 7) & 127, f = idx & 127;
            const float* wp = W_conv + (size_t)map * 2 * DM * DM + f * DM + g;
            Wt[(((size_t)map * 8 + (f >> 4)) * DM + g) * 16 + (f & 15)] = (__bf16)(wp[0] + wp[DM * DM]);
        } else if (idx < 65536) {                // Wot[kc16][d128][16] = W_out[c][d]
            const int k = idx - 32768, d = k >> 8, c = k & 255;
            Wot[(((size_t)(c >> 4)) * DM + d) * 16 + (c & 15)] = (__bf16)W_out[c * DM + d];
        } else if (idx < 65792) {
            const int k = idx - 65536, map = k >> 7, g = k & 127;
            bsum[k] = b_conv[(map * 2) * DM + g] + b_conv[(map * 2 + 1) * DM + g];
        } else if (idx < 66304) {
            bnacc[idx - 65792] = 0.f;
        }
    }
}

// ---------------- fused conv: one block per bs, both maps, full g=128 ----------------
// 448 threads = 7 waves. p1: wave = n-tile (4 g-tiles). p2: wave = m-strip (4 g-tiles).
// x is read by exactly this block (map-1 pass re-hits L1/L2).
// XWS=210 -> LDS 53760 B -> 3 blocks/CU, 768 grid = all resident (zero tail).
__global__ __launch_bounds__(448, 4) void conv_kernel(
    const float* __restrict__ x, const __bf16* __restrict__ Anb,
    const __bf16* __restrict__ Wt, const float* __restrict__ bsum,
    __bf16* __restrict__ h, float* __restrict__ bnacc)
{
    __shared__ __bf16 xw[128 * XWS];              // 53760 B -> 3 blocks/CU
    const int bs = blockIdx.x;
    const int b = bs / SEQ, s = bs % SEQ;
    const int t = threadIdx.x, w = t >> 6, lane = t & 63;
    const int l31 = lane & 31, hi = lane >> 5;

    const int n = w * 32 + l31;
    const bool valid = (n < SENS);
    const float* xrow = x + (((size_t)b * SENS + (valid ? n : 0)) * SEQ + s) * DM + hi * 8;

    float bsn[2][4], bsq[2][4];

    #pragma unroll 1
    for (int map = 0; map < 2; ++map) {
        if (map) __syncthreads();                 // p2(map-1) readers done before rewrite
        // ---- phase 1: xw[g 128][n 208] = Wt[map] @ xr^T (n-tile = w) ----
        {
            f32x16 acc[4];
            #pragma unroll
            for (int gt = 0; gt < 4; ++gt)
                #pragma unroll
                for (int r = 0; r < 16; ++r) acc[gt][r] = 0.f;
            const __bf16* wb = Wt + (((size_t)map * 8) * DM + l31) * 16 + hi * 8;
            #pragma unroll
            for (int kc = 0; kc < 8; ++kc) {
                float4 v0 = *(const float4*)(xrow + kc * 16);
                float4 v1 = *(const float4*)(xrow + kc * 16 + 4);
                bf16x8 bfrag;
                bfrag[0] = (__bf16)v0.x; bfrag[1] = (__bf16)v0.y;
                bfrag[2] = (__bf16)v0.z; bfrag[3] = (__bf16)v0.w;
                bfrag[4] = (__bf16)v1.x; bfrag[5] = (__bf16)v1.y;
                bfrag[6] = (__bf16)v1.z; bfrag[7] = (__bf16)v1.w;
                if (!valid) {
                    #pragma unroll
                    for (int j = 0; j < 8; ++j) bfrag[j] = (__bf16)0.f;
                }
                const __bf16* wp = wb + (size_t)kc * DM * 16;
                #pragma unroll
                for (int gt = 0; gt < 4; ++gt)
                    acc[gt] = mfma32(*(const bf16x8*)(wp + gt * 32 * 16), bfrag, acc[gt]);
            }
            if (n < KP) {
                #pragma unroll
                for (int gt = 0; gt < 4; ++gt)
                    #pragma unroll
                    for (int r = 0; r < 16; ++r) {
                        const int g = gt * 32 + (r & 3) + 8 * (r >> 2) + 4 * hi;
                        xw[g * XWS + n] = (__bf16)acc[gt][r];
                    }
            }
        }
        __syncthreads();

        // ---- phase 2: h-strip w = An[strip] @ xw^T (K=208) ----
        f32x16 acc2[4];
        #pragma unroll
        for (int gt = 0; gt < 4; ++gt)
            #pragma unroll
            for (int r = 0; r < 16; ++r) acc2[gt][r] = 0.f;
        {
            const __bf16* ab = Anb + (((size_t)map * 13) * MPAD + w * 32 + l31) * 16 + hi * 8;
            #pragma unroll 2
            for (int kc = 0; kc < 13; ++kc) {
                bf16x8 afrag = *(const bf16x8*)(ab + (size_t)kc * MPAD * 16);
                #pragma unroll
                for (int gt = 0; gt < 4; ++gt) {
                    bf16x8 bfrag = *(const bf16x8*)(xw + (gt * 32 + l31) * XWS + kc * 16 + hi * 8);
                    acc2[gt] = mfma32(afrag, bfrag, acc2[gt]);
                }
            }
        }
        #pragma unroll
        for (int gt = 0; gt < 4; ++gt) {
            const float bias = bsum[map * DM + gt * 32 + l31];
            bf16x8 h0, h1;
            float s2 = 0.f, q = 0.f;
            #pragma unroll
            for (int r = 0; r < 16; ++r) {
                const float v = acc2[gt][r] + bias;
                if (r < 8) h0[r] = (__bf16)v; else h1[r - 8] = (__bf16)v;
                const int m = w * 32 + (r & 3) + 8 * (r >> 2) + 4 * hi;
                if (m < SENS) { s2 += v; q += v * v; }
            }
            __bf16* hp = h + ((((size_t)(bs * 2 + map) * 7 + w) * 4 + gt) * 64 + lane) * 16;
            *(bf16x8*)hp = h0;
            *(bf16x8*)(hp + 8) = h1;
            s2 += __shfl_xor(s2, 32);
            q += __shfl_xor(q, 32);
            bsn[map][gt] = s2; bsq[map][gt] = q;
        }
    }
    __syncthreads();                     // xw reads done; reuse as reduction buffer
    float* red = (float*)xw;             // [2 map][2 sq][128 g][7 w] = 14336 B
    if (hi == 0) {
        #pragma unroll
        for (int map = 0; map < 2; ++map)
            #pragma unroll
            for (int gt = 0; gt < 4; ++gt) {
                red[(((map * 2 + 0) * 128) + gt * 32 + l31) * 7 + w] = bsn[map][gt];
                red[(((map * 2 + 1) * 128) + gt * 32 + l31) * 7 + w] = bsq[map][gt];
            }
    }
    __syncthreads();
    for (int i = t; i < 512; i += 448) {
        const int map = i >> 8, sq = (i >> 7) & 1, g = i & 127;
        float s2 = 0.f;
        #pragma unroll
        for (int k = 0; k < 7; ++k) s2 += red[i * 7 + k];
        atomicAdd(&bnacc[sq * 256 + map * DM + g], s2);
    }
}

// stage chunk cn of relu(bn(h)) into As buffer (224 rows x 64 cols)
// register-lean: 2-fragment batches (vv live = 8 VGPR) to keep out_kernel <= ~84 VGPR
__device__ __forceinline__ void out_stage(int cn, int t, int bs,
                                          const __bf16* __restrict__ h,
                                          const float* sc_s, const float* sh_s,
                                          __bf16* dst)
{
    const int mapn = cn >> 1;
    const __bf16* hb = h + ((size_t)(bs * 2 + mapn) * 28 + (cn & 1) * 2) * 1024;
    #pragma unroll
    for (int hf = 0; hf < 2; ++hf) {
        bf16x8 vv[2];
        #pragma unroll
        for (int it = 0; it < 2; ++it) {
            const int idx = (hf * 2 + it) * 512 + t;
            if (idx < 1792)
                vv[it] = *(const bf16x8*)(hb + ((size_t)(idx >> 8) * 4 + ((idx >> 7) & 1)) * 1024
                                              + ((idx >> 1) & 63) * 16 + (idx & 1) * 8);
        }
        #pragma unroll
        for (int it = 0; it < 2; ++it) {
            const int idx = (hf * 2 + it) * 512 + t;
            if (idx < 1792) {
                const int half = idx & 1, lane_s = (idx >> 1) & 63;
                const int ctl = (idx >> 7) & 1, strip = idx >> 8;
                const int cl = ctl * 32 + (lane_s & 31);
                const int cg = mapn * DM + (cn & 1) * 64 + cl;
                const float scv = sc_s[cg], shv = sh_s[cg];
                const int mbase = strip * 32 + 4 * (lane_s >> 5) + 16 * half;
                #pragma unroll
                for (int q2 = 0; q2 < 8; ++q2) {
                    const int row = mbase + (q2 & 3) + 8 * (q2 >> 2);
                    const float fv = (float)vv[it][q2] * scv + shv;
                    dst[row * ASROW + cl] = (__bf16)fmaxf(fv, 0.f);
                }
            }
        }
    }
}

// ---------------- out: relu( relu(bn(h)) cat @ W_out + b_out ), single-buffered ----------------
// As single buffer: LDS 30464+2048 = 32512 B -> up to 4 blocks/CU (wave-capped),
// grid 768 = 3 resident/CU (zero tail) if VGPR <= ~84.
__global__ __launch_bounds__(512) void out_kernel(
    const __bf16* __restrict__ h, const __bf16* __restrict__ Wot,
    const float* __restrict__ bnacc,
    const float* __restrict__ gamma, const float* __restrict__ beta,
    const float* __restrict__ b_out, float* __restrict__ out)
{
    __shared__ __bf16 As[MPAD * ASROW];           // 30464 B
    __shared__ float sc_s[256], sh_s[256];
    const int bs = blockIdx.x;
    const int b = bs / SEQ, s = bs % SEQ;
    const int t = threadIdx.x, w = t >> 6, lane = t & 63;
    const int l31 = lane & 31, hi = lane >> 5;
    const int dct = w & 3, sbase = w >> 2;
    if (t < 256) {                                // BN finalize (fused, per-block)
        const float mu = bnacc[t] * (1.f / (float)NTOT);
        const float var = bnacc[256 + t] * (1.f / (float)NTOT) - mu * mu;
        const float sc = gamma[t] * rsqrtf(var + BN_EPS);
        sc_s[t] = sc;
        sh_s[t] = beta[t] - mu * sc;
    }
    f32x16 acc[4];
    {
        const float bo = b_out[dct * 32 + l31];
        #pragma unroll
        for (int i = 0; i < 4; ++i)
            #pragma unroll
            for (int r = 0; r < 16; ++r) acc[i][r] = bo;
    }
    __syncthreads();
    for (int c = 0; c < 4; ++c) {
        out_stage(c, t, bs, h, sc_s, sh_s, &As[0]);
        __syncthreads();
        #pragma unroll
        for (int kc = 0; kc < 4; ++kc) {
            bf16x8 bfrag = *(const bf16x8*)(Wot + ((size_t)(c * 4 + kc) * DM + dct * 32 + l31) * 16 + hi * 8);
            #pragma unroll
            for (int i = 0; i < 4; ++i) {
                const int strip = sbase + 2 * i;
                if (strip >= 7) break;
                const __bf16* ap = &As[(strip * 32 + l31) * ASROW + kc * 16 + hi * 8];
                acc[i] = mfma32(join8(*(const bf16x4*)ap, *(const bf16x4*)(ap + 4)), bfrag, acc[i]);
            }
        }
        if (c < 3) __syncthreads();               // As reads done before next overwrite
    }
    #pragma unroll
    for (int i = 0; i < 4; ++i) {
        const int strip = sbase + 2 * i;
        if (strip >= 7) break;
        #pragma unroll
        for (int r = 0; r < 16; ++r) {
            const int m = strip * 32 + (r & 3) + 8 * (r >> 2) + 4 * hi;
            if (m < SENS)
                out[(((size_t)b * SENS + m) * SEQ + s) * DM + dct * 32 + l31] = fmaxf(acc[i][r], 0.f);
        }
    }
}

extern "C" void kernel_launch(void* const* d_in, const int* in_sizes, int n_in,
                              void* d_out, int out_size, void* d_ws, size_t ws_size,
                              hipStream_t stream) {
    const float* x        = (const float*)d_in[0];
    const float* attn     = (const float*)d_in[1];
    const float* supports = (const float*)d_in[2];
    const float* W_conv   = (const float*)d_in[3];
    const float* b_conv   = (const float*)d_in[4];
    const float* gamma    = (const float*)d_in[5];
    const float* beta     = (const float*)d_in[6];
    const float* W_out    = (const float*)d_in[7];
    const float* b_out    = (const float*)d_in[8];
    float* out = (float*)d_out;
    char* base = (char*)d_ws;

    float*  mapA  = (float*)(base + 0);          // 160000
    float*  Mbuf  = (float*)(base + 160000);     // 320000
    float*  deg   = (float*)(base + 480000);     // 1600
    float*  bnacc = (float*)(base + 481664);     // 2048
    float*  bsum  = (float*)(base + 483712);     // 1024
    __bf16* Wt    = (__bf16*)(base + 484736);    // 65536
    __bf16* Wot   = (__bf16*)(base + 550272);    // 65536
    __bf16* Anb   = (__bf16*)(base + 615808);    // 186368
    __bf16* h     = (__bf16*)(base + 1048576);   // 88080384 (end ~85 MiB)

    attn_mean_kernel<<<157, 256, 0, stream>>>(attn, mapA);
    build_map_kernel<<<dim3(SENS, 2), 256, 0, stream>>>(supports, mapA, Mbuf, deg);
    prep2_kernel<<<2 * MPAD + 260, 256, 0, stream>>>(Mbuf, deg, W_conv, b_conv, W_out,
                                                     Anb, Wt, Wot, bsum, bnacc);
    conv_kernel<<<BS, 448, 0, stream>>>(x, Anb, Wt, bsum, h, bnacc);
    out_kernel<<<BS, 512, 0, stream>>>(h, Wot, bnacc, gamma, beta, b_out, out);
}

// Round 6
// 257.082 us; speedup vs baseline: 1.2651x; 1.0192x over previous
//
#include <hip/hip_runtime.h>

#define SENS 200
#define DM 128
#define SEQ 96
#define NB 8
#define BS 768            // NB*SEQ
#define NTOT 153600       // BS*SENS
#define TH 0.01f
#define BN_EPS 1e-5f
#define MPAD 224          // padded sensor dim (7*32)
#define KP 208            // effective K for phase2 / xw cols (13*16)
#define XWS 208           // xw LDS row stride (416 B = 104 dw). b128 reads: 16-B windows
                          // uniform over 8 positions -> zero bank penalty; b16 writes 2-way (free).
                          // 128*208*2 = 53248 B = 26 x 2KiB granules -> 3 blocks/CU with slack.
#define ASROW 68          // out As stride (136 B = 34 dw, gcd 2 -> free)

typedef __attribute__((ext_vector_type(8)))  __bf16 bf16x8;
typedef __attribute__((ext_vector_type(4)))  __bf16 bf16x4;
typedef __attribute__((ext_vector_type(16))) float  f32x16;

__device__ __forceinline__ f32x16 mfma32(bf16x8 a, bf16x8 b, f32x16 c) {
    return __builtin_amdgcn_mfma_f32_32x32x16_bf16(a, b, c, 0, 0, 0);
}
__device__ __forceinline__ bf16x8 join8(bf16x4 a, bf16x4 b) {
    bf16x8 r;
    #pragma unroll
    for (int j = 0; j < 4; ++j) { r[j] = a[j]; r[j + 4] = b[j]; }
    return r;
}

// ---------------- mean over 64 attention maps ----------------
__global__ void attn_mean_kernel(const float* __restrict__ attn, float* __restrict__ mapA) {
    int idx = blockIdx.x * 256 + threadIdx.x;
    if (idx >= SENS * SENS) return;
    float s = 0.f;
    #pragma unroll 8
    for (int q = 0; q < 64; ++q) s += attn[(size_t)q * SENS * SENS + idx];
    mapA[idx] = s * (1.0f / 64.0f);
}

// ---------------- symmetrize + clamp + degree ----------------
__global__ void build_map_kernel(const float* __restrict__ supports, const float* __restrict__ mapA,
                                 float* __restrict__ M, float* __restrict__ deg) {
    __shared__ float red[256];
    int m = blockIdx.x, map = blockIdx.y, j = threadIdx.x;
    const float* src = (map == 0) ? supports : mapA;
    float v = 0.f;
    if (j < SENS) {
        float sym = (m >= j) ? src[m * SENS + j] : src[j * SENS + m];
        float a = fabsf(sym);
        v = (a > TH) ? a : 0.f;
        M[(size_t)map * SENS * SENS + m * SENS + j] = v;
    }
    red[j] = v;
    __syncthreads();
    for (int off = 128; off > 0; off >>= 1) {
        if (j < off) red[j] += red[j + off];
        __syncthreads();
    }
    if (j == 0) deg[map * SENS + m] = red[0] + 1.0f;   // + self-loop
}

// ---------------- prep: An bf16 (K-sliced) | weights/bias/bnacc ----------------
__global__ __launch_bounds__(256) void prep2_kernel(
    const float* __restrict__ M, const float* __restrict__ deg,
    const float* __restrict__ W_conv, const float* __restrict__ b_conv,
    const float* __restrict__ W_out,
    __bf16* __restrict__ Anb, __bf16* __restrict__ Wt, __bf16* __restrict__ Wot,
    float* __restrict__ bsum, float* __restrict__ bnacc)
{
    const int bid = blockIdx.x, t = threadIdx.x;
    if (bid < 2 * MPAD) {
        // Anb[map][kc13][m 224][16]
        const int map = bid / MPAD, m = bid % MPAD;
        const int j = t;
        if (j < KP) {
            float val = 0.f;
            if (m < SENS && j < SENS) {
                float a = M[((size_t)map * SENS + m) * SENS + j] + ((m == j) ? 1.f : 0.f);
                val = rsqrtf(deg[map * SENS + m]) * a * rsqrtf(deg[map * SENS + j]);
            }
            Anb[(((size_t)map * 13 + (j >> 4)) * MPAD + m) * 16 + (j & 15)] = (__bf16)val;
        }
    } else {
        const int idx = (bid - 2 * MPAD) * 256 + t;
        if (idx < 32768) {                       // Wt[map][kc8][g128][16] = sum_l W[map][l][f][g]
            const int map = idx >> 14, g = (idx >> 7) & 127, f = idx & 127;
            const float* wp = W_conv + (size_t)map * 2 * DM * DM + f * DM + g;
            Wt[(((size_t)map * 8 + (f >> 4)) * DM + g) * 16 + (f & 15)] = (__bf16)(wp[0] + wp[DM * DM]);
        } else if (idx < 65536) {                // Wot[kc16][d128][16] = W_out[c][d]
            const int k = idx - 32768, d = k >> 8, c = k & 255;
            Wot[(((size_t)(c >> 4)) * DM + d) * 16 + (c & 15)] = (__bf16)W_out[c * DM + d];
        } else if (idx < 65792) {
            const int k = idx - 65536, map = k >> 7, g = k & 127;
            bsum[k] = b_conv[(map * 2) * DM + g] + b_conv[(map * 2 + 1) * DM + g];
        } else if (idx < 66304) {
            bnacc[idx - 65792] = 0.f;
        }
    }
}

// ---------------- fused conv: one block per bs, both maps, full g=128 ----------------
// 448 threads = 7 waves. p1: wave = n-tile (4 g-tiles). p2: wave = m-strip (4 g-tiles).
// x is read by exactly this block (map-1 pass re-hits L1/L2).
// XWS=208 -> LDS 53248 B (26 x 2KiB granules) -> 3 blocks/CU, 768 grid = all resident.
__global__ __launch_bounds__(448, 4) void conv_kernel(
    const float* __restrict__ x, const __bf16* __restrict__ Anb,
    const __bf16* __restrict__ Wt, const float* __restrict__ bsum,
    __bf16* __restrict__ h, float* __restrict__ bnacc)
{
    __shared__ __bf16 xw[128 * XWS];              // 53248 B -> 3 blocks/CU
    const int bs = blockIdx.x;
    const int b = bs / SEQ, s = bs % SEQ;
    const int t = threadIdx.x, w = t >> 6, lane = t & 63;
    const int l31 = lane & 31, hi = lane >> 5;

    const int n = w * 32 + l31;
    const bool valid = (n < SENS);
    const float* xrow = x + (((size_t)b * SENS + (valid ? n : 0)) * SEQ + s) * DM + hi * 8;

    float bsn[2][4], bsq[2][4];

    #pragma unroll 1
    for (int map = 0; map < 2; ++map) {
        if (map) __syncthreads();                 // p2(map-1) readers done before rewrite
        // ---- phase 1: xw[g 128][n 208] = Wt[map] @ xr^T (n-tile = w) ----
        {
            f32x16 acc[4];
            #pragma unroll
            for (int gt = 0; gt < 4; ++gt)
                #pragma unroll
                for (int r = 0; r < 16; ++r) acc[gt][r] = 0.f;
            const __bf16* wb = Wt + (((size_t)map * 8) * DM + l31) * 16 + hi * 8;
            #pragma unroll
            for (int kc = 0; kc < 8; ++kc) {
                float4 v0 = *(const float4*)(xrow + kc * 16);
                float4 v1 = *(const float4*)(xrow + kc * 16 + 4);
                bf16x8 bfrag;
                bfrag[0] = (__bf16)v0.x; bfrag[1] = (__bf16)v0.y;
                bfrag[2] = (__bf16)v0.z; bfrag[3] = (__bf16)v0.w;
                bfrag[4] = (__bf16)v1.x; bfrag[5] = (__bf16)v1.y;
                bfrag[6] = (__bf16)v1.z; bfrag[7] = (__bf16)v1.w;
                if (!valid) {
                    #pragma unroll
                    for (int j = 0; j < 8; ++j) bfrag[j] = (__bf16)0.f;
                }
                const __bf16* wp = wb + (size_t)kc * DM * 16;
                #pragma unroll
                for (int gt = 0; gt < 4; ++gt)
                    acc[gt] = mfma32(*(const bf16x8*)(wp + gt * 32 * 16), bfrag, acc[gt]);
            }
            if (n < KP) {
                #pragma unroll
                for (int gt = 0; gt < 4; ++gt)
                    #pragma unroll
                    for (int r = 0; r < 16; ++r) {
                        const int g = gt * 32 + (r & 3) + 8 * (r >> 2) + 4 * hi;
                        xw[g * XWS + n] = (__bf16)acc[gt][r];
                    }
            }
        }
        __syncthreads();

        // ---- phase 2: h-strip w = An[strip] @ xw^T (K=208) ----
        f32x16 acc2[4];
        #pragma unroll
        for (int gt = 0; gt < 4; ++gt)
            #pragma unroll
            for (int r = 0; r < 16; ++r) acc2[gt][r] = 0.f;
        {
            const __bf16* ab = Anb + (((size_t)map * 13) * MPAD + w * 32 + l31) * 16 + hi * 8;
            #pragma unroll 2
            for (int kc = 0; kc < 13; ++kc) {
                bf16x8 afrag = *(const bf16x8*)(ab + (size_t)kc * MPAD * 16);
                #pragma unroll
                for (int gt = 0; gt < 4; ++gt) {
                    bf16x8 bfrag = *(const bf16x8*)(xw + (gt * 32 + l31) * XWS + kc * 16 + hi * 8);
                    acc2[gt] = mfma32(afrag, bfrag, acc2[gt]);
                }
            }
        }
        #pragma unroll
        for (int gt = 0; gt < 4; ++gt) {
            const float bias = bsum[map * DM + gt * 32 + l31];
            bf16x8 h0, h1;
            float s2 = 0.f, q = 0.f;
            #pragma unroll
            for (int r = 0; r < 16; ++r) {
                const float v = acc2[gt][r] + bias;
                if (r < 8) h0[r] = (__bf16)v; else h1[r - 8] = (__bf16)v;
                const int m = w * 32 + (r & 3) + 8 * (r >> 2) + 4 * hi;
                if (m < SENS) { s2 += v; q += v * v; }
            }
            __bf16* hp = h + ((((size_t)(bs * 2 + map) * 7 + w) * 4 + gt) * 64 + lane) * 16;
            *(bf16x8*)hp = h0;
            *(bf16x8*)(hp + 8) = h1;
            s2 += __shfl_xor(s2, 32);
            q += __shfl_xor(q, 32);
            bsn[map][gt] = s2; bsq[map][gt] = q;
        }
    }
    __syncthreads();                     // xw reads done; reuse as reduction buffer
    float* red = (float*)xw;             // [2 map][2 sq][128 g][7 w] = 14336 B
    if (hi == 0) {
        #pragma unroll
        for (int map = 0; map < 2; ++map)
            #pragma unroll
            for (int gt = 0; gt < 4; ++gt) {
                red[(((map * 2 + 0) * 128) + gt * 32 + l31) * 7 + w] = bsn[map][gt];
                red[(((map * 2 + 1) * 128) + gt * 32 + l31) * 7 + w] = bsq[map][gt];
            }
    }
    __syncthreads();
    for (int i = t; i < 512; i += 448) {
        const int map = i >> 8, sq = (i >> 7) & 1, g = i & 127;
        float s2 = 0.f;
        #pragma unroll
        for (int k = 0; k < 7; ++k) s2 += red[i * 7 + k];
        atomicAdd(&bnacc[sq * 256 + map * DM + g], s2);
    }
}

// stage chunk cn of relu(bn(h)) into As buffer (224 rows x 64 cols)
// register-lean: 2-fragment batches (vv live = 8 VGPR) to keep out_kernel <= ~84 VGPR
__device__ __forceinline__ void out_stage(int cn, int t, int bs,
                                          const __bf16* __restrict__ h,
                                          const float* sc_s, const float* sh_s,
                                          __bf16* dst)
{
    const int mapn = cn >> 1;
    const __bf16* hb = h + ((size_t)(bs * 2 + mapn) * 28 + (cn & 1) * 2) * 1024;
    #pragma unroll
    for (int hf = 0; hf < 2; ++hf) {
        bf16x8 vv[2];
        #pragma unroll
        for (int it = 0; it < 2; ++it) {
            const int idx = (hf * 2 + it) * 512 + t;
            if (idx < 1792)
                vv[it] = *(const bf16x8*)(hb + ((size_t)(idx >> 8) * 4 + ((idx >> 7) & 1)) * 1024
                                              + ((idx >> 1) & 63) * 16 + (idx & 1) * 8);
        }
        #pragma unroll
        for (int it = 0; it < 2; ++it) {
            const int idx = (hf * 2 + it) * 512 + t;
            if (idx < 1792) {
                const int half = idx & 1, lane_s = (idx >> 1) & 63;
                const int ctl = (idx >> 7) & 1, strip = idx >> 8;
                const int cl = ctl * 32 + (lane_s & 31);
                const int cg = mapn * DM + (cn & 1) * 64 + cl;
                const float scv = sc_s[cg], shv = sh_s[cg];
                const int mbase = strip * 32 + 4 * (lane_s >> 5) + 16 * half;
                #pragma unroll
                for (int q2 = 0; q2 < 8; ++q2) {
                    const int row = mbase + (q2 & 3) + 8 * (q2 >> 2);
                    const float fv = (float)vv[it][q2] * scv + shv;
                    dst[row * ASROW + cl] = (__bf16)fmaxf(fv, 0.f);
                }
            }
        }
    }
}

// ---------------- out: relu( relu(bn(h)) cat @ W_out + b_out ), single-buffered ----------------
// As single buffer: LDS 30464+2048 = 32512 B -> up to 4 blocks/CU (wave-capped),
// grid 768 = 3 resident/CU (zero tail) if VGPR <= ~84.
__global__ __launch_bounds__(512) void out_kernel(
    const __bf16* __restrict__ h, const __bf16* __restrict__ Wot,
    const float* __restrict__ bnacc,
    const float* __restrict__ gamma, const float* __restrict__ beta,
    const float* __restrict__ b_out, float* __restrict__ out)
{
    __shared__ __bf16 As[MPAD * ASROW];           // 30464 B
    __shared__ float sc_s[256], sh_s[256];
    const int bs = blockIdx.x;
    const int b = bs / SEQ, s = bs % SEQ;
    const int t = threadIdx.x, w = t >> 6, lane = t & 63;
    const int l31 = lane & 31, hi = lane >> 5;
    const int dct = w & 3, sbase = w >> 2;
    if (t < 256) {                                // BN finalize (fused, per-block)
        const float mu = bnacc[t] * (1.f / (float)NTOT);
        const float var = bnacc[256 + t] * (1.f / (float)NTOT) - mu * mu;
        const float sc = gamma[t] * rsqrtf(var + BN_EPS);
        sc_s[t] = sc;
        sh_s[t] = beta[t] - mu * sc;
    }
    f32x16 acc[4];
    {
        const float bo = b_out[dct * 32 + l31];
        #pragma unroll
        for (int i = 0; i < 4; ++i)
            #pragma unroll
            for (int r = 0; r < 16; ++r) acc[i][r] = bo;
    }
    __syncthreads();
    for (int c = 0; c < 4; ++c) {
        out_stage(c, t, bs, h, sc_s, sh_s, &As[0]);
        __syncthreads();
        #pragma unroll
        for (int kc = 0; kc < 4; ++kc) {
            bf16x8 bfrag = *(const bf16x8*)(Wot + ((size_t)(c * 4 + kc) * DM + dct * 32 + l31) * 16 + hi * 8);
            #pragma unroll
            for (int i = 0; i < 4; ++i) {
                const int strip = sbase + 2 * i;
                if (strip >= 7) break;
                const __bf16* ap = &As[(strip * 32 + l31) * ASROW + kc * 16 + hi * 8];
                acc[i] = mfma32(join8(*(const bf16x4*)ap, *(const bf16x4*)(ap + 4)), bfrag, acc[i]);
            }
        }
        if (c < 3) __syncthreads();               // As reads done before next overwrite
    }
    #pragma unroll
    for (int i = 0; i < 4; ++i) {
        const int strip = sbase + 2 * i;
        if (strip >= 7) break;
        #pragma unroll
        for (int r = 0; r < 16; ++r) {
            const int m = strip * 32 + (r & 3) + 8 * (r >> 2) + 4 * hi;
            if (m < SENS)
                out[(((size_t)b * SENS + m) * SEQ + s) * DM + dct * 32 + l31] = fmaxf(acc[i][r], 0.f);
        }
    }
}

extern "C" void kernel_launch(void* const* d_in, const int* in_sizes, int n_in,
                              void* d_out, int out_size, void* d_ws, size_t ws_size,
                              hipStream_t stream) {
    const float* x        = (const float*)d_in[0];
    const float* attn     = (const float*)d_in[1];
    const float* supports = (const float*)d_in[2];
    const float* W_conv   = (const float*)d_in[3];
    const float* b_conv   = (const float*)d_in[4];
    const float* gamma    = (const float*)d_in[5];
    const float* beta     = (const float*)d_in[6];
    const float* W_out    = (const float*)d_in[7];
    const float* b_out    = (const float*)d_in[8];
    float* out = (float*)d_out;
    char* base = (char*)d_ws;

    float*  mapA  = (float*)(base + 0);          // 160000
    float*  Mbuf  = (float*)(base + 160000);     // 320000
    float*  deg   = (float*)(base + 480000);     // 1600
    float*  bnacc = (float*)(base + 481664);     // 2048
    float*  bsum  = (float*)(base + 483712);     // 1024
    __bf16* Wt    = (__bf16*)(base + 484736);    // 65536
    __bf16* Wot   = (__bf16*)(base + 550272);    // 65536
    __bf16* Anb   = (__bf16*)(base + 615808);    // 186368
    __bf16* h     = (__bf16*)(base + 1048576);   // 88080384 (end ~85 MiB)

    attn_mean_kernel<<<157, 256, 0, stream>>>(attn, mapA);
    build_map_kernel<<<dim3(SENS, 2), 256, 0, stream>>>(supports, mapA, Mbuf, deg);
    prep2_kernel<<<2 * MPAD + 260, 256, 0, stream>>>(Mbuf, deg, W_conv, b_conv, W_out,
                                                     Anb, Wt, Wot, bsum, bnacc);
    conv_kernel<<<BS, 448, 0, stream>>>(x, Anb, Wt, bsum, h, bnacc);
    out_kernel<<<BS, 512, 0, stream>>>(h, Wot, bnacc, gamma, beta, b_out, out);
}